// Round 9
// baseline (354.880 us; speedup 1.0000x reference)
//
#include <hip/hip_runtime.h>

#define LN 262144
#define LMASK 262143
#define NCH 64
#define NB 512
#define INV_L (1.0f/262144.0f)
#define BSTR 38    // fwd LDS stride (halfs): write<=2-way, read<=2-way banks
#define ISTR 138   // inv Bs stride (halfs): reads <=2-way
#define XSTR 66    // inv xpose stride (floats): ~conflict-free both sides

typedef short short8 __attribute__((ext_vector_type(8)));
typedef float f32x4 __attribute__((ext_vector_type(4)));

union s8i4 { int4 i; short8 s; };

// pack two f32 -> two bf16 (truncation round) in ONE v_perm_b32
static __device__ __forceinline__ unsigned pkbf(float lo, float hi) {
    union { float f; unsigned u; } a, b; a.f = lo; b.f = hi;
    return __builtin_amdgcn_perm(b.u, a.u, 0x07060302u);
}
static __device__ __forceinline__ short8 pk8(const float* v) {
    s8i4 cv;
    cv.i = make_int4(pkbf(v[0], v[1]), pkbf(v[2], v[3]),
                     pkbf(v[4], v[5]), pkbf(v[6], v[7]));
    return cv.s;
}
static __device__ __forceinline__ unsigned short f2bf_t(float x) {  // truncate
    union { float f; unsigned u; } v; v.f = x;
    return (unsigned short)(v.u >> 16);
}
static __device__ __forceinline__ float bf2f(unsigned short b) {
    union { unsigned u; float f; } v; v.u = ((unsigned)b) << 16;
    return v.f;
}
static __device__ __forceinline__ float fsin01(float rev) {  // sin(2*pi*rev)
    float r; asm("v_sin_f32 %0, %1" : "=v"(r) : "v"(rev)); return r;
}
static __device__ __forceinline__ float fcos01(float rev) {  // cos(2*pi*rev)
    float r; asm("v_cos_f32 %0, %1" : "=v"(r) : "v"(rev)); return r;
}

// device-scope grid barrier. Safe: launch_bounds(256,2) guarantees all 512
// blocks co-resident (2/CU). __threadfence = agent fence -> cross-XCD L2
// writeback/invalidate around the atomic.
static __device__ __forceinline__ void gbar(unsigned* __restrict__ ctr, unsigned target) {
    __syncthreads();
    __threadfence();
    if (threadIdx.x == 0) {
        atomicAdd(ctr, 1u);
        while (__hip_atomic_load(ctr, __ATOMIC_RELAXED, __HIP_MEMORY_SCOPE_AGENT) < target)
            __builtin_amdgcn_s_sleep(2);
    }
    __syncthreads();
    __threadfence();
}

__global__ __launch_bounds__(256, 2) void fno_fused(
        const float* __restrict__ u, const float* __restrict__ y,
        const float* __restrict__ Kt, const float* __restrict__ W,
        unsigned short* __restrict__ part, float* __restrict__ uhat,
        float* __restrict__ coef, unsigned* __restrict__ ctr,
        float* __restrict__ out) {
    __shared__ __align__(16) char smem[35072];
    const int tid = threadIdx.x;
    const int blk = blockIdx.x;
    const int lane = tid & 63;
    const int w = tid >> 6;
    const int l15 = lane & 15;
    const int hk = lane >> 4;
    const unsigned NBLK = gridDim.x;   // 512

    // ================= Phase 1: forward DFT partials =================
    {
        unsigned short* BtB = (unsigned short*)smem;   // 2 x [64*BSTR]
        const int chunk = LN / NB;          // 512
        const int ksteps = chunk >> 5;      // 16
        const int n0 = blk * chunk;
        const int kkst = tid >> 3;
        const int gst = tid & 7;
        const int m = w * 16 + l15;

        float cR[8], nsR[8];
        #pragma unroll
        for (int j = 0; j < 8; ++j) {
            int ph = (m * (n0 + hk * 8 + j)) & LMASK;
            cR[j] = fcos01((float)ph * INV_L);
            nsR[j] = -fsin01((float)ph * INV_L);
        }
        float cD, sD;
        {
            int ph = (m * 32) & LMASK;
            cD = fcos01((float)ph * INV_L);
            sD = fsin01((float)ph * INV_L);
        }
        f32x4 accC[4], accS[4];
        #pragma unroll
        for (int t = 0; t < 4; ++t) { accC[t] = (f32x4){0,0,0,0}; accS[t] = (f32x4){0,0,0,0}; }

        const float* __restrict__ ub = u + (size_t)(n0 + kkst) * NCH + gst * 8;
        const size_t tstep = 32 * NCH;

        float4 a0 = *(const float4*)(ub);
        float4 a1 = *(const float4*)(ub + 4);
        float4 b0 = *(const float4*)(ub + tstep);
        float4 b1 = *(const float4*)(ub + tstep + 4);
        {
            float uv[8] = {a0.x, a0.y, a0.z, a0.w, a1.x, a1.y, a1.z, a1.w};
            #pragma unroll
            for (int q = 0; q < 8; ++q)
                BtB[(gst * 8 + q) * BSTR + kkst] = f2bf_t(uv[q]);
        }
        a0 = b0; a1 = b1;
        b0 = *(const float4*)(ub + 2 * tstep);
        b1 = *(const float4*)(ub + 2 * tstep + 4);

        for (int t = 0; t < ksteps; ++t) {
            __syncthreads();
            if (t + 1 < ksteps) {
                float uv[8] = {a0.x, a0.y, a0.z, a0.w, a1.x, a1.y, a1.z, a1.w};
                unsigned short* bt = BtB + ((t + 1) & 1) * (64 * BSTR);
                #pragma unroll
                for (int q = 0; q < 8; ++q)
                    bt[(gst * 8 + q) * BSTR + kkst] = f2bf_t(uv[q]);
            }
            a0 = b0; a1 = b1;
            if (t + 3 < ksteps) {
                const float* pn = ub + (size_t)(t + 3) * tstep;
                b0 = *(const float4*)(pn);
                b1 = *(const float4*)(pn + 4);
            }
            const short8 aC = pk8(cR);
            const short8 aS = pk8(nsR);
            #pragma unroll
            for (int j = 0; j < 8; ++j) {
                float c2 = cR[j] * cD + nsR[j] * sD;
                nsR[j] = nsR[j] * cD - cR[j] * sD;
                cR[j] = c2;
            }
            const unsigned short* bt = BtB + (t & 1) * (64 * BSTR);
            #pragma unroll
            for (int tn = 0; tn < 4; ++tn) {
                const short8 bf = *(const short8*)&bt[(tn * 16 + l15) * BSTR + hk * 8];
                accC[tn] = __builtin_amdgcn_mfma_f32_16x16x32_bf16(aC, bf, accC[tn], 0, 0, 0);
                accS[tn] = __builtin_amdgcn_mfma_f32_16x16x32_bf16(aS, bf, accS[tn], 0, 0, 0);
            }
        }
        unsigned short* baseR = part + (size_t)blk * 8192;
        #pragma unroll
        for (int tn = 0; tn < 4; ++tn) {
            #pragma unroll
            for (int r = 0; r < 4; ++r) {
                int k = w * 16 + hk * 4 + r;
                int i = tn * 16 + l15;
                baseR[k * 64 + i] = f2bf_t(accC[tn][r]);
                baseR[4096 + k * 64 + i] = f2bf_t(accS[tn][r]);
            }
        }
    }
    gbar(ctr, NBLK);

    // ================= Phase 2: reduce partials -> uhat =================
    {
        float (*red)[18] = (float(*)[18])smem;   // 130 rows x 18
        const int g0 = blk * 16;
        const int sp = tid & 1;
        const int bi = tid >> 1;     // 0..127
        float acc[8] = {0,0,0,0,0,0,0,0};
        for (int b = bi; b < NB; b += 128) {
            short8 v = *(const short8*)&part[(size_t)b * 8192 + g0 + sp * 8];
            #pragma unroll
            for (int e = 0; e < 8; ++e)
                acc[e] += bf2f((unsigned short)v[e]);
        }
        #pragma unroll
        for (int e = 0; e < 8; ++e)
            red[bi][sp * 8 + e] = acc[e];
        __syncthreads();
        if (tid < 32) {
            const int g = tid & 15, h = tid >> 4;
            float s = 0.f;
            #pragma unroll 16
            for (int r = h * 64; r < h * 64 + 64; ++r)
                s += red[r][g];
            red[128 + h][g] = s;
        }
        __syncthreads();
        if (tid < 16)
            uhat[g0 + tid] = red[128][tid] + red[129][tid];
    }
    gbar(ctr, 2 * NBLK);

    // ================= Phase 3: Kc apply + z_local =================
    if (blk < 64) {
        float* zr4 = (float*)smem;          // [4][64]
        float* zi4 = zr4 + 256;             // [4][64]
        float* reS = zi4 + 256;             // [64]
        float* imS = reS + 64;              // [64]
        const int k = blk;
        const int o = tid & 63;
        const int q = tid >> 6;
        if (tid < 64) { reS[tid] = uhat[k * 64 + tid]; imS[tid] = uhat[4096 + k * 64 + tid]; }
        __syncthreads();
        float zr = 0.f, zi = 0.f;
        #pragma unroll 4
        for (int ii = q * 16; ii < q * 16 + 16; ++ii) {
            float k0v = Kt[(size_t)(ii * 64 + o) * 64 + k];
            float k1v = Kt[262144 + (size_t)(ii * 64 + o) * 64 + k];
            zr = fmaf(reS[ii], k0v, fmaf(-imS[ii], k1v, zr));
            zi = fmaf(reS[ii], k1v, fmaf(imS[ii], k0v, zi));
        }
        zr4[q * 64 + o] = zr;
        zi4[q * 64 + o] = zi;
        __syncthreads();
        if (tid < 64) {
            float zrs = zr4[tid] + zr4[64 + tid] + zr4[128 + tid] + zr4[192 + tid];
            float zis = zi4[tid] + zi4[64 + tid] + zi4[128 + tid] + zi4[192 + tid];
            if (k == 0) {
                coef[tid] = zrs * INV_L;    // DC: only Re enters irfft
                coef[4096 + tid] = 0.f;
            } else {
                coef[k * 64 + tid] = 2.f * zrs * INV_L;
                coef[4096 + k * 64 + tid] = -2.f * zis * INV_L;
            }
        }
    } else if (blk == 64) {
        float* zl4 = (float*)smem;          // [4][64]
        const int o = tid & 63;
        const int q = tid >> 6;
        const int idx = (int)(y[0] * (float)LN);
        float zl = 0.f;
        #pragma unroll 4
        for (int ii = q * 16; ii < q * 16 + 16; ++ii)
            zl = fmaf(W[o * 64 + ii], u[(size_t)idx * 64 + ii], zl);
        zl4[q * 64 + o] = zl;
        __syncthreads();
        if (tid < 64)
            coef[8192 + tid] = zl4[tid] + zl4[64 + tid] + zl4[128 + tid] + zl4[192 + tid];
    }
    gbar(ctr, 3 * NBLK);

    // ================= Phase 4: inverse transform =================
    {
        unsigned short* Bs = (unsigned short*)smem;            // 64*ISTR halfs
        float* zloc = (float*)(smem + 64 * ISTR * 2);          // 64 f
        float* xpw = (float*)(smem + 17920) + w * 16 * XSTR;   // per-wave

        for (int e = tid; e < 4096; e += 256) {
            int mm = e >> 6, ch = e & 63;
            Bs[ch * ISTR + mm] = f2bf_t(coef[e]);
            Bs[ch * ISTR + 64 + mm] = f2bf_t(coef[4096 + e]);
        }
        if (tid < 64) zloc[tid] = coef[8192 + tid];
        __syncthreads();

        const int rl = lane >> 4;
        const int cq = lane & 15;
        float4 zv = *(const float4*)&zloc[cq * 4];

        // hoist p-invariant B fragments into registers (16 x ds_read_b128, once)
        short8 bfr[4][4];
        #pragma unroll
        for (int ks = 0; ks < 4; ++ks)
            #pragma unroll
            for (int tn = 0; tn < 4; ++tn)
                bfr[ks][tn] = *(const short8*)&Bs[(tn * 16 + l15) * ISTR + ks * 32 + hk * 8];

        for (int p = 0; p < 8; ++p) {
            const int nbase = blk * 512 + (p * 4 + w) * 16;
            const int row = nbase + l15;
            float cstp = fcos01((float)row * INV_L);
            float sstp = fsin01((float)row * INV_L);

            short8 aF[4];
            #pragma unroll
            for (int h = 0; h < 2; ++h) {
                const int m0 = h * 32 + hk * 8;
                const int ph = (row * m0) & LMASK;
                float c = fcos01((float)ph * INV_L);
                float s = fsin01((float)ph * INV_L);
                float cv[8], sv[8];
                #pragma unroll
                for (int jj = 0; jj < 8; ++jj) {
                    cv[jj] = c; sv[jj] = s;
                    float c2 = c * cstp - s * sstp;
                    s = fmaf(s, cstp, c * sstp);
                    c = c2;
                }
                aF[h] = pk8(cv);
                aF[2 + h] = pk8(sv);
            }

            f32x4 acc[4];
            #pragma unroll
            for (int tn = 0; tn < 4; ++tn) acc[tn] = (f32x4){0,0,0,0};
            #pragma unroll
            for (int ks = 0; ks < 4; ++ks)
                #pragma unroll
                for (int tn = 0; tn < 4; ++tn)
                    acc[tn] = __builtin_amdgcn_mfma_f32_16x16x32_bf16(aF[ks], bfr[ks][tn], acc[tn], 0, 0, 0);

            #pragma unroll
            for (int tn = 0; tn < 4; ++tn)
                #pragma unroll
                for (int r = 0; r < 4; ++r)
                    xpw[(hk * 4 + r) * XSTR + tn * 16 + l15] = acc[tn][r];
            asm volatile("s_waitcnt lgkmcnt(0)" ::: "memory");
            #pragma unroll
            for (int rg = 0; rg < 4; ++rg) {
                const int rowl = rg * 4 + rl;
                float4 v = *(const float4*)&xpw[rowl * XSTR + cq * 4];
                v.x += zv.x; v.y += zv.y; v.z += zv.z; v.w += zv.w;
                *(float4*)(out + (size_t)(nbase + rowl) * NCH + cq * 4) = v;
            }
        }
    }
}

extern "C" void kernel_launch(void* const* d_in, const int* in_sizes, int n_in,
                              void* d_out, int out_size, void* d_ws, size_t ws_size,
                              hipStream_t stream) {
    const float* u = (const float*)d_in[0];
    const float* y = (const float*)d_in[1];
    const float* K = (const float*)d_in[2];
    const float* W = (const float*)d_in[3];
    float* out = (float*)d_out;

    // ws layout (ws >= 16.8 MB, proven by R6's nb=1024 actually running):
    // part bf16 [512][8192] @0 (8388608 B) | uhat f32 8192 | coef f32 8256 | ctr @9 MiB
    unsigned short* part = (unsigned short*)d_ws;
    float* uhat = (float*)((char*)d_ws + 8388608);
    float* coef = (float*)((char*)d_ws + 8388608 + 32768);
    unsigned* ctr = (unsigned*)((char*)d_ws + 9437184);

    hipMemsetAsync(ctr, 0, 128, stream);
    fno_fused<<<NB, 256, 0, stream>>>(u, y, K, W, part, uhat, coef, ctr, out);
}

// Round 10
// 136.614 us; speedup vs baseline: 2.5977x; 2.5977x over previous
//
#include <hip/hip_runtime.h>

#define LN 262144
#define LMASK 262143
#define NCH 64
#define NB 512
#define INV_L (1.0f/262144.0f)
#define BSTR 38    // fwd LDS stride (halfs): write<=2-way, read<=2-way banks
#define ISTR 138   // inv Bs stride (halfs): reads <=2-way
#define XSTR 66    // inv xpose stride (floats): ~conflict-free both sides

typedef short short8 __attribute__((ext_vector_type(8)));
typedef float f32x4 __attribute__((ext_vector_type(4)));

union s8i4 { int4 i; short8 s; };

// pack two f32 -> two bf16 (truncation round) in ONE v_perm_b32
static __device__ __forceinline__ unsigned pkbf(float lo, float hi) {
    union { float f; unsigned u; } a, b; a.f = lo; b.f = hi;
    return __builtin_amdgcn_perm(b.u, a.u, 0x07060302u);
}
static __device__ __forceinline__ short8 pk8(const float* v) {
    s8i4 cv;
    cv.i = make_int4(pkbf(v[0], v[1]), pkbf(v[2], v[3]),
                     pkbf(v[4], v[5]), pkbf(v[6], v[7]));
    return cv.s;
}
static __device__ __forceinline__ unsigned short f2bf_t(float x) {  // truncate
    union { float f; unsigned u; } v; v.f = x;
    return (unsigned short)(v.u >> 16);
}
static __device__ __forceinline__ float bf2f(unsigned short b) {
    union { unsigned u; float f; } v; v.u = ((unsigned)b) << 16;
    return v.f;
}
static __device__ __forceinline__ float fsin01(float rev) {  // sin(2*pi*rev)
    float r; asm("v_sin_f32 %0, %1" : "=v"(r) : "v"(rev)); return r;
}
static __device__ __forceinline__ float fcos01(float rev) {  // cos(2*pi*rev)
    float r; asm("v_cos_f32 %0, %1" : "=v"(r) : "v"(rev)); return r;
}

// Grid barrier, ONE L2 flush per block per side (not per wave):
// __syncthreads drains all waves' stores into L2 (compiler emits vmcnt(0)
// before s_barrier); thread 0's RELEASE fetch_add does one buffer_wbl2 +
// atomic; RELAXED spin (no repeated inv); ONE acquire fence (buffer_inv)
// before releasing the block. Co-resident proof: launch_bounds(256,2),
// 512 blocks = 2/CU x 256 CUs.
static __device__ __forceinline__ void gbar(unsigned* __restrict__ ctr, unsigned target) {
    __syncthreads();
    if (threadIdx.x == 0) {
        __hip_atomic_fetch_add(ctr, 1u, __ATOMIC_RELEASE, __HIP_MEMORY_SCOPE_AGENT);
        while (__hip_atomic_load(ctr, __ATOMIC_RELAXED, __HIP_MEMORY_SCOPE_AGENT) < target)
            __builtin_amdgcn_s_sleep(4);
        __builtin_amdgcn_fence(__ATOMIC_ACQUIRE, "agent");
    }
    __syncthreads();
}

__global__ __launch_bounds__(256, 2) void fno_fused(
        const float* __restrict__ u, const float* __restrict__ y,
        const float* __restrict__ Kt, const float* __restrict__ W,
        unsigned short* __restrict__ part, float* __restrict__ coef,
        unsigned* __restrict__ ctr, float* __restrict__ out) {
    __shared__ __align__(16) char smem[35072];
    const int tid = threadIdx.x;
    const int blk = blockIdx.x;
    const int lane = tid & 63;
    const int w = tid >> 6;
    const int l15 = lane & 15;
    const int hk = lane >> 4;
    const unsigned NBLK = gridDim.x;   // 512

    // ================= Phase 1: forward DFT partials =================
    {
        unsigned short* BtB = (unsigned short*)smem;   // 2 x [64*BSTR]
        const int chunk = LN / NB;          // 512
        const int ksteps = chunk >> 5;      // 16
        const int n0 = blk * chunk;
        const int kkst = tid >> 3;
        const int gst = tid & 7;
        const int m = w * 16 + l15;

        float cR[8], nsR[8];
        #pragma unroll
        for (int j = 0; j < 8; ++j) {
            int ph = (m * (n0 + hk * 8 + j)) & LMASK;
            cR[j] = fcos01((float)ph * INV_L);
            nsR[j] = -fsin01((float)ph * INV_L);
        }
        float cD, sD;
        {
            int ph = (m * 32) & LMASK;
            cD = fcos01((float)ph * INV_L);
            sD = fsin01((float)ph * INV_L);
        }
        f32x4 accC[4], accS[4];
        #pragma unroll
        for (int t = 0; t < 4; ++t) { accC[t] = (f32x4){0,0,0,0}; accS[t] = (f32x4){0,0,0,0}; }

        const float* __restrict__ ub = u + (size_t)(n0 + kkst) * NCH + gst * 8;
        const size_t tstep = 32 * NCH;

        float4 a0 = *(const float4*)(ub);
        float4 a1 = *(const float4*)(ub + 4);
        float4 b0 = *(const float4*)(ub + tstep);
        float4 b1 = *(const float4*)(ub + tstep + 4);
        {
            float uv[8] = {a0.x, a0.y, a0.z, a0.w, a1.x, a1.y, a1.z, a1.w};
            #pragma unroll
            for (int q = 0; q < 8; ++q)
                BtB[(gst * 8 + q) * BSTR + kkst] = f2bf_t(uv[q]);
        }
        a0 = b0; a1 = b1;
        b0 = *(const float4*)(ub + 2 * tstep);
        b1 = *(const float4*)(ub + 2 * tstep + 4);

        for (int t = 0; t < ksteps; ++t) {
            __syncthreads();
            if (t + 1 < ksteps) {
                float uv[8] = {a0.x, a0.y, a0.z, a0.w, a1.x, a1.y, a1.z, a1.w};
                unsigned short* bt = BtB + ((t + 1) & 1) * (64 * BSTR);
                #pragma unroll
                for (int q = 0; q < 8; ++q)
                    bt[(gst * 8 + q) * BSTR + kkst] = f2bf_t(uv[q]);
            }
            a0 = b0; a1 = b1;
            if (t + 3 < ksteps) {
                const float* pn = ub + (size_t)(t + 3) * tstep;
                b0 = *(const float4*)(pn);
                b1 = *(const float4*)(pn + 4);
            }
            const short8 aC = pk8(cR);
            const short8 aS = pk8(nsR);
            #pragma unroll
            for (int j = 0; j < 8; ++j) {
                float c2 = cR[j] * cD + nsR[j] * sD;
                nsR[j] = nsR[j] * cD - cR[j] * sD;
                cR[j] = c2;
            }
            const unsigned short* bt = BtB + (t & 1) * (64 * BSTR);
            #pragma unroll
            for (int tn = 0; tn < 4; ++tn) {
                const short8 bf = *(const short8*)&bt[(tn * 16 + l15) * BSTR + hk * 8];
                accC[tn] = __builtin_amdgcn_mfma_f32_16x16x32_bf16(aC, bf, accC[tn], 0, 0, 0);
                accS[tn] = __builtin_amdgcn_mfma_f32_16x16x32_bf16(aS, bf, accS[tn], 0, 0, 0);
            }
        }
        unsigned short* baseR = part + (size_t)blk * 8192;
        #pragma unroll
        for (int tn = 0; tn < 4; ++tn) {
            #pragma unroll
            for (int r = 0; r < 4; ++r) {
                int k = w * 16 + hk * 4 + r;
                int i = tn * 16 + l15;
                baseR[k * 64 + i] = f2bf_t(accC[tn][r]);
                baseR[4096 + k * 64 + i] = f2bf_t(accS[tn][r]);
            }
        }
    }
    gbar(ctr, NBLK);

    // ========= Phase 2+3: per-mode reduce + Kc apply (blocks 0..63), z_local (64) =========
    if (blk < 64) {
        float (*red)[130] = (float(*)[130])smem;           // [16][130]
        float* uh = (float*)(smem + 16 * 130 * 4);         // [128]
        float* zr4 = uh + 128;                             // [4][64]
        float* zi4 = zr4 + 256;                            // [4][64]
        const int k = blk;
        const int j = tid & 15;       // short8 slot: 0..7 re, 8..15 im
        const int h = tid >> 4;       // 16-way b-interleave
        const size_t slot = (size_t)k * 64 + (j & 7) * 8 + ((j >> 3) ? 4096 : 0);

        float acc[8] = {0,0,0,0,0,0,0,0};
        for (int b = h; b < NB; b += 16) {
            short8 v = *(const short8*)&part[(size_t)b * 8192 + slot];
            #pragma unroll
            for (int e = 0; e < 8; ++e)
                acc[e] += bf2f((unsigned short)v[e]);
        }
        #pragma unroll
        for (int e = 0; e < 8; ++e)
            red[h][j * 8 + e] = acc[e];
        __syncthreads();
        if (tid < 128) {
            float s = 0.f;
            #pragma unroll
            for (int hh = 0; hh < 16; ++hh)
                s += red[hh][tid];
            uh[tid] = s;
        }
        __syncthreads();
        {   // Kc apply: o = tid&63, q = tid>>6 splits the ii-sum 4 ways
            const int o = tid & 63;
            const int q = tid >> 6;
            float zr = 0.f, zi = 0.f;
            #pragma unroll 4
            for (int ii = q * 16; ii < q * 16 + 16; ++ii) {
                float k0v = Kt[(size_t)(ii * 64 + o) * 64 + k];
                float k1v = Kt[262144 + (size_t)(ii * 64 + o) * 64 + k];
                zr = fmaf(uh[ii], k0v, fmaf(-uh[64 + ii], k1v, zr));
                zi = fmaf(uh[ii], k1v, fmaf(uh[64 + ii], k0v, zi));
            }
            zr4[q * 64 + o] = zr;
            zi4[q * 64 + o] = zi;
        }
        __syncthreads();
        if (tid < 64) {
            float zrs = zr4[tid] + zr4[64 + tid] + zr4[128 + tid] + zr4[192 + tid];
            float zis = zi4[tid] + zi4[64 + tid] + zi4[128 + tid] + zi4[192 + tid];
            if (k == 0) {
                coef[tid] = zrs * INV_L;    // DC: only Re enters irfft
                coef[4096 + tid] = 0.f;
            } else {
                coef[k * 64 + tid] = 2.f * zrs * INV_L;
                coef[4096 + k * 64 + tid] = -2.f * zis * INV_L;
            }
        }
    } else if (blk == 64) {
        float* zl4 = (float*)smem;          // [4][64]
        const int o = tid & 63;
        const int q = tid >> 6;
        const int idx = (int)(y[0] * (float)LN);
        float zl = 0.f;
        #pragma unroll 4
        for (int ii = q * 16; ii < q * 16 + 16; ++ii)
            zl = fmaf(W[o * 64 + ii], u[(size_t)idx * 64 + ii], zl);
        zl4[q * 64 + o] = zl;
        __syncthreads();
        if (tid < 64)
            coef[8192 + tid] = zl4[tid] + zl4[64 + tid] + zl4[128 + tid] + zl4[192 + tid];
    }
    gbar(ctr, 2 * NBLK);

    // ================= Phase 4: inverse transform =================
    {
        unsigned short* Bs = (unsigned short*)smem;            // 64*ISTR halfs
        float* zloc = (float*)(smem + 64 * ISTR * 2);          // 64 f
        float* xpw = (float*)(smem + 17920) + w * 16 * XSTR;   // per-wave

        for (int e = tid; e < 4096; e += 256) {
            int mm = e >> 6, ch = e & 63;
            Bs[ch * ISTR + mm] = f2bf_t(coef[e]);
            Bs[ch * ISTR + 64 + mm] = f2bf_t(coef[4096 + e]);
        }
        if (tid < 64) zloc[tid] = coef[8192 + tid];
        __syncthreads();

        const int rl = lane >> 4;
        const int cq = lane & 15;
        float4 zv = *(const float4*)&zloc[cq * 4];

        // hoist p-invariant B fragments into registers (16 x ds_read_b128, once)
        short8 bfr[4][4];
        #pragma unroll
        for (int ks = 0; ks < 4; ++ks)
            #pragma unroll
            for (int tn = 0; tn < 4; ++tn)
                bfr[ks][tn] = *(const short8*)&Bs[(tn * 16 + l15) * ISTR + ks * 32 + hk * 8];

        for (int p = 0; p < 8; ++p) {
            const int nbase = blk * 512 + (p * 4 + w) * 16;
            const int row = nbase + l15;
            float cstp = fcos01((float)row * INV_L);
            float sstp = fsin01((float)row * INV_L);

            short8 aF[4];
            #pragma unroll
            for (int h = 0; h < 2; ++h) {
                const int m0 = h * 32 + hk * 8;
                const int ph = (row * m0) & LMASK;
                float c = fcos01((float)ph * INV_L);
                float s = fsin01((float)ph * INV_L);
                float cv[8], sv[8];
                #pragma unroll
                for (int jj = 0; jj < 8; ++jj) {
                    cv[jj] = c; sv[jj] = s;
                    float c2 = c * cstp - s * sstp;
                    s = fmaf(s, cstp, c * sstp);
                    c = c2;
                }
                aF[h] = pk8(cv);
                aF[2 + h] = pk8(sv);
            }

            f32x4 acc[4];
            #pragma unroll
            for (int tn = 0; tn < 4; ++tn) acc[tn] = (f32x4){0,0,0,0};
            #pragma unroll
            for (int ks = 0; ks < 4; ++ks)
                #pragma unroll
                for (int tn = 0; tn < 4; ++tn)
                    acc[tn] = __builtin_amdgcn_mfma_f32_16x16x32_bf16(aF[ks], bfr[ks][tn], acc[tn], 0, 0, 0);

            #pragma unroll
            for (int tn = 0; tn < 4; ++tn)
                #pragma unroll
                for (int r = 0; r < 4; ++r)
                    xpw[(hk * 4 + r) * XSTR + tn * 16 + l15] = acc[tn][r];
            asm volatile("s_waitcnt lgkmcnt(0)" ::: "memory");
            #pragma unroll
            for (int rg = 0; rg < 4; ++rg) {
                const int rowl = rg * 4 + rl;
                float4 v = *(const float4*)&xpw[rowl * XSTR + cq * 4];
                v.x += zv.x; v.y += zv.y; v.z += zv.z; v.w += zv.w;
                *(float4*)(out + (size_t)(nbase + rowl) * NCH + cq * 4) = v;
            }
        }
    }
}

extern "C" void kernel_launch(void* const* d_in, const int* in_sizes, int n_in,
                              void* d_out, int out_size, void* d_ws, size_t ws_size,
                              hipStream_t stream) {
    const float* u = (const float*)d_in[0];
    const float* y = (const float*)d_in[1];
    const float* K = (const float*)d_in[2];
    const float* W = (const float*)d_in[3];
    float* out = (float*)d_out;

    // ws layout: part bf16 [512][8192] @0 (8 MiB) | coef f32 8256 | ctr @9 MiB
    unsigned short* part = (unsigned short*)d_ws;
    float* coef = (float*)((char*)d_ws + 8388608);
    unsigned* ctr = (unsigned*)((char*)d_ws + 9437184);

    hipMemsetAsync(ctr, 0, 128, stream);
    fno_fused<<<NB, 256, 0, stream>>>(u, y, K, W, part, coef, ctr, out);
}

// Round 11
// 86.671 us; speedup vs baseline: 4.0945x; 1.5762x over previous
//
#include <hip/hip_runtime.h>

#define LN 262144
#define LMASK 262143
#define NCH 64
#define NBF 512     // fwd blocks
#define INV_L (1.0f/262144.0f)
#define BSTR 38     // fwd LDS stride (halfs)
#define ISTR 138    // inv Bs stride (halfs)
#define XSTR 66     // inv xpose stride (floats)

typedef short short8 __attribute__((ext_vector_type(8)));
typedef float f32x4 __attribute__((ext_vector_type(4)));

union s8i4 { int4 i; short8 s; };

// pack two f32 -> two bf16 (truncation) in ONE v_perm_b32
static __device__ __forceinline__ unsigned pkbf(float lo, float hi) {
    union { float f; unsigned u; } a, b; a.f = lo; b.f = hi;
    return __builtin_amdgcn_perm(b.u, a.u, 0x07060302u);
}
static __device__ __forceinline__ short8 pk8(const float* v) {
    s8i4 cv;
    cv.i = make_int4(pkbf(v[0], v[1]), pkbf(v[2], v[3]),
                     pkbf(v[4], v[5]), pkbf(v[6], v[7]));
    return cv.s;
}
static __device__ __forceinline__ unsigned short f2bf_t(float x) {
    union { float f; unsigned u; } v; v.f = x;
    return (unsigned short)(v.u >> 16);
}
static __device__ __forceinline__ float bf2f(unsigned short b) {
    union { unsigned u; float f; } v; v.u = ((unsigned)b) << 16;
    return v.f;
}
static __device__ __forceinline__ float fsin01(float rev) {
    float r; asm("v_sin_f32 %0, %1" : "=v"(r) : "v"(rev)); return r;
}
static __device__ __forceinline__ float fcos01(float rev) {
    float r; asm("v_cos_f32 %0, %1" : "=v"(r) : "v"(rev)); return r;
}

// ================= K1: fwd (blocks 0..511) + reduce/Kc/z_local (512..576) ==============
// part_w[b*4096 + k*64 + i] = u32( Re_bf16 | Im_bf16<<16 ), written with
// agent-scope relaxed atomic stores (sc1 -> coherence point, no L2 flush walk).
__global__ __launch_bounds__(256, 2) void fno_fwdred(
        const float* __restrict__ u, const float* __restrict__ y,
        const float* __restrict__ Kt, const float* __restrict__ W,
        unsigned* __restrict__ part_w, float* __restrict__ coef,
        unsigned* __restrict__ ctr) {
    __shared__ __align__(16) char smem[12544];
    const int tid = threadIdx.x;
    const int bid = blockIdx.x;
    const int lane = tid & 63;
    const int w = tid >> 6;
    const int l15 = lane & 15;
    const int hk = lane >> 4;

    if (bid < NBF) {
        // ---------------- forward DFT partials ----------------
        unsigned short* BtB = (unsigned short*)smem;   // 2 x [64*BSTR]
        const int chunk = LN / NBF;          // 512
        const int ksteps = chunk >> 5;       // 16
        const int n0 = bid * chunk;
        const int kkst = tid >> 3;
        const int gst = tid & 7;
        const int m = w * 16 + l15;

        float cR[8], nsR[8];
        #pragma unroll
        for (int j = 0; j < 8; ++j) {
            int ph = (m * (n0 + hk * 8 + j)) & LMASK;
            cR[j] = fcos01((float)ph * INV_L);
            nsR[j] = -fsin01((float)ph * INV_L);
        }
        float cD, sD;
        {
            int ph = (m * 32) & LMASK;
            cD = fcos01((float)ph * INV_L);
            sD = fsin01((float)ph * INV_L);
        }
        f32x4 accC[4], accS[4];
        #pragma unroll
        for (int t = 0; t < 4; ++t) { accC[t] = (f32x4){0,0,0,0}; accS[t] = (f32x4){0,0,0,0}; }

        const float* __restrict__ ub = u + (size_t)(n0 + kkst) * NCH + gst * 8;
        const size_t tstep = 32 * NCH;

        float4 a0 = *(const float4*)(ub);
        float4 a1 = *(const float4*)(ub + 4);
        float4 b0 = *(const float4*)(ub + tstep);
        float4 b1 = *(const float4*)(ub + tstep + 4);
        {
            float uv[8] = {a0.x, a0.y, a0.z, a0.w, a1.x, a1.y, a1.z, a1.w};
            #pragma unroll
            for (int q = 0; q < 8; ++q)
                BtB[(gst * 8 + q) * BSTR + kkst] = f2bf_t(uv[q]);
        }
        a0 = b0; a1 = b1;
        b0 = *(const float4*)(ub + 2 * tstep);
        b1 = *(const float4*)(ub + 2 * tstep + 4);

        for (int t = 0; t < ksteps; ++t) {
            __syncthreads();
            if (t + 1 < ksteps) {
                float uv[8] = {a0.x, a0.y, a0.z, a0.w, a1.x, a1.y, a1.z, a1.w};
                unsigned short* bt = BtB + ((t + 1) & 1) * (64 * BSTR);
                #pragma unroll
                for (int q = 0; q < 8; ++q)
                    bt[(gst * 8 + q) * BSTR + kkst] = f2bf_t(uv[q]);
            }
            a0 = b0; a1 = b1;
            if (t + 3 < ksteps) {
                const float* pn = ub + (size_t)(t + 3) * tstep;
                b0 = *(const float4*)(pn);
                b1 = *(const float4*)(pn + 4);
            }
            const short8 aC = pk8(cR);
            const short8 aS = pk8(nsR);
            #pragma unroll
            for (int j = 0; j < 8; ++j) {
                float c2 = cR[j] * cD + nsR[j] * sD;
                nsR[j] = nsR[j] * cD - cR[j] * sD;
                cR[j] = c2;
            }
            const unsigned short* bt = BtB + (t & 1) * (64 * BSTR);
            #pragma unroll
            for (int tn = 0; tn < 4; ++tn) {
                const short8 bf = *(const short8*)&bt[(tn * 16 + l15) * BSTR + hk * 8];
                accC[tn] = __builtin_amdgcn_mfma_f32_16x16x32_bf16(aC, bf, accC[tn], 0, 0, 0);
                accS[tn] = __builtin_amdgcn_mfma_f32_16x16x32_bf16(aS, bf, accS[tn], 0, 0, 0);
            }
        }
        // epilogue: (Re,Im) packed u32, agent-scope relaxed stores (sc1)
        unsigned* basew = part_w + (size_t)bid * 4096;
        #pragma unroll
        for (int tn = 0; tn < 4; ++tn) {
            #pragma unroll
            for (int r = 0; r < 4; ++r) {
                int k = w * 16 + hk * 4 + r;
                int i = tn * 16 + l15;
                unsigned word = pkbf(accC[tn][r], accS[tn][r]);  // lo=Re, hi=Im
                __hip_atomic_store(&basew[k * 64 + i], word,
                                   __ATOMIC_RELAXED, __HIP_MEMORY_SCOPE_AGENT);
            }
        }
        // release: implicit per-wave vmcnt(0) at the barrier drains sc1 stores,
        // then one relaxed counter add.
        __syncthreads();
        if (tid == 0)
            __hip_atomic_fetch_add(ctr, 1u, __ATOMIC_RELAXED, __HIP_MEMORY_SCOPE_AGENT);
        return;
    }

    // ---------------- trailing blocks: wait for all fwd partials ----------------
    if (tid == 0) {
        while (__hip_atomic_load(ctr, __ATOMIC_RELAXED, __HIP_MEMORY_SCOPE_AGENT) < NBF)
            __builtin_amdgcn_s_sleep(8);
        __builtin_amdgcn_fence(__ATOMIC_ACQUIRE, "agent");   // one buffer_inv
    }
    __syncthreads();

    const int cb = bid - NBF;   // 0..64
    if (cb < 64) {
        // reduce mode k across 512 blocks + Kc apply
        float (*redR)[68] = (float(*)[68])smem;                  // [16][68]
        float (*redI)[68] = (float(*)[68])(smem + 4352);         // [16][68]
        float* uh  = (float*)(smem + 8704);                      // [128]
        float* zr4 = uh + 128;                                   // [4][64]
        float* zi4 = zr4 + 256;                                  // [4][64]
        const int k = cb;
        const int i4 = tid & 15;      // i = i4*4
        const int h = tid >> 4;       // 0..15 b-interleave

        float aR[4] = {0,0,0,0}, aI[4] = {0,0,0,0};
        for (int b = h; b < NBF; b += 16) {
            uint4 v = *(const uint4*)&part_w[(size_t)b * 4096 + k * 64 + i4 * 4];
            unsigned vv[4] = {v.x, v.y, v.z, v.w};
            #pragma unroll
            for (int e = 0; e < 4; ++e) {
                aR[e] += bf2f((unsigned short)(vv[e] & 0xffff));
                aI[e] += bf2f((unsigned short)(vv[e] >> 16));
            }
        }
        #pragma unroll
        for (int e = 0; e < 4; ++e) { redR[h][i4 * 4 + e] = aR[e]; redI[h][i4 * 4 + e] = aI[e]; }
        __syncthreads();
        if (tid < 128) {
            const int i = tid & 63;
            float s = 0.f;
            if (tid < 64) {
                #pragma unroll
                for (int hh = 0; hh < 16; ++hh) s += redR[hh][i];
            } else {
                #pragma unroll
                for (int hh = 0; hh < 16; ++hh) s += redI[hh][i];
            }
            uh[tid] = s;
        }
        __syncthreads();
        {   // Kc apply: o = tid&63, q = tid>>6 splits ii-sum 4 ways
            const int o = tid & 63;
            const int q = tid >> 6;
            float zr = 0.f, zi = 0.f;
            #pragma unroll 4
            for (int ii = q * 16; ii < q * 16 + 16; ++ii) {
                float k0v = Kt[(size_t)(ii * 64 + o) * 64 + k];
                float k1v = Kt[262144 + (size_t)(ii * 64 + o) * 64 + k];
                zr = fmaf(uh[ii], k0v, fmaf(-uh[64 + ii], k1v, zr));
                zi = fmaf(uh[ii], k1v, fmaf(uh[64 + ii], k0v, zi));
            }
            zr4[q * 64 + o] = zr;
            zi4[q * 64 + o] = zi;
        }
        __syncthreads();
        if (tid < 64) {
            float zrs = zr4[tid] + zr4[64 + tid] + zr4[128 + tid] + zr4[192 + tid];
            float zis = zi4[tid] + zi4[64 + tid] + zi4[128 + tid] + zi4[192 + tid];
            if (k == 0) {
                coef[tid] = zrs * INV_L;    // DC: only Re enters irfft
                coef[4096 + tid] = 0.f;
            } else {
                coef[k * 64 + tid] = 2.f * zrs * INV_L;
                coef[4096 + k * 64 + tid] = -2.f * zis * INV_L;
            }
        }
    } else {
        // z_local
        float* zl4 = (float*)smem;          // [4][64]
        const int o = tid & 63;
        const int q = tid >> 6;
        const int idx = (int)(y[0] * (float)LN);
        float zl = 0.f;
        #pragma unroll 4
        for (int ii = q * 16; ii < q * 16 + 16; ++ii)
            zl = fmaf(W[o * 64 + ii], u[(size_t)idx * 64 + ii], zl);
        zl4[q * 64 + o] = zl;
        __syncthreads();
        if (tid < 64)
            coef[8192 + tid] = zl4[tid] + zl4[64 + tid] + zl4[128 + tid] + zl4[192 + tid];
    }
}

// ================= K2: inverse transform =================
__global__ __launch_bounds__(256, 3) void fno_inv(const float* __restrict__ coef,
                                                  float* __restrict__ out) {
    __shared__ __align__(16) char ismem[17920];
    unsigned short* Bs = (unsigned short*)ismem;          // 64*ISTR halfs (prologue only)
    float* zloc = (float*)(ismem + 17664);                // 64 f
    const int tid = threadIdx.x;
    const int lane = tid & 63;
    const int w = tid >> 6;
    const int l15 = lane & 15;
    const int hk = lane >> 4;

    for (int e = tid; e < 4096; e += 256) {
        int mm = e >> 6, ch = e & 63;
        Bs[ch * ISTR + mm] = f2bf_t(coef[e]);
        Bs[ch * ISTR + 64 + mm] = f2bf_t(coef[4096 + e]);
    }
    if (tid < 64) zloc[tid] = coef[8192 + tid];
    __syncthreads();

    const int rl = lane >> 4;
    const int cq = lane & 15;
    float4 zv = *(const float4*)&zloc[cq * 4];

    // hoist p-invariant B fragments into registers (once)
    short8 bfr[4][4];
    #pragma unroll
    for (int ks = 0; ks < 4; ++ks)
        #pragma unroll
        for (int tn = 0; tn < 4; ++tn)
            bfr[ks][tn] = *(const short8*)&Bs[(tn * 16 + l15) * ISTR + ks * 32 + hk * 8];
    __syncthreads();   // barrier drains lgkmcnt -> safe to alias xpose over Bs

    float* xpw = (float*)ismem + w * 16 * XSTR;   // per-wave xpose region

    for (int p = 0; p < 4; ++p) {
        const int nbase = blockIdx.x * 256 + (p * 4 + w) * 16;
        const int row = nbase + l15;
        float cstp = fcos01((float)row * INV_L);
        float sstp = fsin01((float)row * INV_L);

        short8 aF[4];
        #pragma unroll
        for (int h = 0; h < 2; ++h) {
            const int m0 = h * 32 + hk * 8;
            const int ph = (row * m0) & LMASK;
            float c = fcos01((float)ph * INV_L);
            float s = fsin01((float)ph * INV_L);
            float cv[8], sv[8];
            #pragma unroll
            for (int jj = 0; jj < 8; ++jj) {
                cv[jj] = c; sv[jj] = s;
                float c2 = c * cstp - s * sstp;
                s = fmaf(s, cstp, c * sstp);
                c = c2;
            }
            aF[h] = pk8(cv);
            aF[2 + h] = pk8(sv);
        }

        f32x4 acc[4];
        #pragma unroll
        for (int tn = 0; tn < 4; ++tn) acc[tn] = (f32x4){0,0,0,0};
        #pragma unroll
        for (int ks = 0; ks < 4; ++ks)
            #pragma unroll
            for (int tn = 0; tn < 4; ++tn)
                acc[tn] = __builtin_amdgcn_mfma_f32_16x16x32_bf16(aF[ks], bfr[ks][tn], acc[tn], 0, 0, 0);

        #pragma unroll
        for (int tn = 0; tn < 4; ++tn)
            #pragma unroll
            for (int r = 0; r < 4; ++r)
                xpw[(hk * 4 + r) * XSTR + tn * 16 + l15] = acc[tn][r];
        asm volatile("s_waitcnt lgkmcnt(0)" ::: "memory");
        #pragma unroll
        for (int rg = 0; rg < 4; ++rg) {
            const int rowl = rg * 4 + rl;
            float4 v = *(const float4*)&xpw[rowl * XSTR + cq * 4];
            v.x += zv.x; v.y += zv.y; v.z += zv.z; v.w += zv.w;
            *(float4*)(out + (size_t)(nbase + rowl) * NCH + cq * 4) = v;
        }
        __syncthreads();
    }
}

extern "C" void kernel_launch(void* const* d_in, const int* in_sizes, int n_in,
                              void* d_out, int out_size, void* d_ws, size_t ws_size,
                              hipStream_t stream) {
    const float* u = (const float*)d_in[0];
    const float* y = (const float*)d_in[1];
    const float* K = (const float*)d_in[2];
    const float* W = (const float*)d_in[3];
    float* out = (float*)d_out;

    // ws: part_w u32[512*4096] @0 (8 MiB) | coef f32 8256 @8 MiB | ctr @9 MiB
    unsigned* part_w = (unsigned*)d_ws;
    float* coef = (float*)((char*)d_ws + 8388608);
    unsigned* ctr = (unsigned*)((char*)d_ws + 9437184);

    hipMemsetAsync(ctr, 0, 4, stream);
    fno_fwdred<<<NBF + 65, 256, 0, stream>>>(u, y, K, W, part_w, coef, ctr);
    fno_inv<<<1024, 256, 0, stream>>>(coef, out);
}

// Round 12
// 63.930 us; speedup vs baseline: 5.5511x; 1.3557x over previous
//
#include <hip/hip_runtime.h>

#define LN 262144
#define LMASK 262143
#define NCH 64
#define NBF 512     // fwd blocks
#define INV_L (1.0f/262144.0f)
#define BSTR 38     // fwd LDS stride (halfs)
#define ISTR 138    // inv Bs stride (halfs)
#define XSTR 66     // inv xpose stride (floats)

typedef short short8 __attribute__((ext_vector_type(8)));
typedef float f32x4 __attribute__((ext_vector_type(4)));

union s8i4 { int4 i; short8 s; };

// pack two f32 -> two bf16 (truncation) in ONE v_perm_b32
static __device__ __forceinline__ unsigned pkbf(float lo, float hi) {
    union { float f; unsigned u; } a, b; a.f = lo; b.f = hi;
    return __builtin_amdgcn_perm(b.u, a.u, 0x07060302u);
}
static __device__ __forceinline__ short8 pk8(const float* v) {
    s8i4 cv;
    cv.i = make_int4(pkbf(v[0], v[1]), pkbf(v[2], v[3]),
                     pkbf(v[4], v[5]), pkbf(v[6], v[7]));
    return cv.s;
}
static __device__ __forceinline__ unsigned short f2bf_t(float x) {
    union { float f; unsigned u; } v; v.f = x;
    return (unsigned short)(v.u >> 16);
}
static __device__ __forceinline__ float bf2f(unsigned short b) {
    union { unsigned u; float f; } v; v.u = ((unsigned)b) << 16;
    return v.f;
}
static __device__ __forceinline__ float fsin01(float rev) {
    float r; asm("v_sin_f32 %0, %1" : "=v"(r) : "v"(rev)); return r;
}
static __device__ __forceinline__ float fcos01(float rev) {
    float r; asm("v_cos_f32 %0, %1" : "=v"(r) : "v"(rev)); return r;
}

// ================= K1: forward DFT partials via MFMA =================
// 512 blocks x 256 thr. 64-row SUPER-steps: one barrier per 2 sub-tiles.
// Loads for super t+2 issue at step t, consumed at step t+1 -> ~1 full
// step (>1000 cyc) of latency cover despite the vmcnt(0) barrier drain.
// part_w[b*4096 + k*64 + i] = u32( Re_bf16 | Im_bf16<<16 ).
__global__ __launch_bounds__(256, 2) void fno_fwd(const float* __restrict__ u,
                                                  unsigned* __restrict__ part_w) {
    __shared__ __align__(16) unsigned short Bt[4][64 * BSTR];
    const int tid = threadIdx.x;
    const int lane = tid & 63;
    const int w = tid >> 6;
    const int l15 = lane & 15;
    const int hk = lane >> 4;
    const int kkst = tid >> 3;   // staging row 0..31
    const int gst = tid & 7;     // staging channel group
    const int n0 = blockIdx.x * 512;
    const int m = w * 16 + l15;  // this lane's mode

    float cR[8], nsR[8];
    #pragma unroll
    for (int j = 0; j < 8; ++j) {
        int ph = (m * (n0 + hk * 8 + j)) & LMASK;
        cR[j] = fcos01((float)ph * INV_L);
        nsR[j] = -fsin01((float)ph * INV_L);
    }
    float cD, sD;
    {
        int ph = (m * 32) & LMASK;
        cD = fcos01((float)ph * INV_L);
        sD = fsin01((float)ph * INV_L);
    }

    f32x4 accC[4], accS[4];
    #pragma unroll
    for (int t = 0; t < 4; ++t) { accC[t] = (f32x4){0,0,0,0}; accS[t] = (f32x4){0,0,0,0}; }

    const float* __restrict__ ub = u + (size_t)(n0 + kkst) * NCH + gst * 8;
    const size_t sub = 32 * NCH;      // 32-row stride
    const size_t sup = 64 * NCH;      // 64-row stride

#define STAGE(BUF, VA, VB) do {                                            \
        float uv_[8] = {(VA).x, (VA).y, (VA).z, (VA).w,                    \
                        (VB).x, (VB).y, (VB).z, (VB).w};                   \
        _Pragma("unroll")                                                  \
        for (int q_ = 0; q_ < 8; ++q_)                                     \
            Bt[BUF][(gst * 8 + q_) * BSTR + kkst] = f2bf_t(uv_[q_]);       \
    } while (0)

    // prologue: stage super 0 -> pair 0; load super 1 into regs
    float4 r0a = *(const float4*)(ub);
    float4 r0b = *(const float4*)(ub + 4);
    float4 r1a = *(const float4*)(ub + sub);
    float4 r1b = *(const float4*)(ub + sub + 4);
    STAGE(0, r0a, r0b);
    STAGE(1, r1a, r1b);
    r0a = *(const float4*)(ub + sup);
    r0b = *(const float4*)(ub + sup + 4);
    r1a = *(const float4*)(ub + sup + sub);
    r1b = *(const float4*)(ub + sup + sub + 4);

    for (int ss = 0; ss < 8; ++ss) {
        __syncthreads();
        const int cp = ss & 1;            // compute pair
        if (ss + 1 < 8) {                 // stage super ss+1 -> other pair
            STAGE((cp ^ 1) * 2 + 0, r0a, r0b);
            STAGE((cp ^ 1) * 2 + 1, r1a, r1b);
        }
        if (ss + 2 < 8) {                 // issue loads for super ss+2
            const float* pn = ub + (size_t)(ss + 2) * sup;
            r0a = *(const float4*)(pn);
            r0b = *(const float4*)(pn + 4);
            r1a = *(const float4*)(pn + sub);
            r1b = *(const float4*)(pn + sub + 4);
        }
        #pragma unroll
        for (int st = 0; st < 2; ++st) {  // two 32-row sub-tiles
            const short8 aC = pk8(cR);
            const short8 aS = pk8(nsR);
            #pragma unroll
            for (int j = 0; j < 8; ++j) {   // advance rotation by 32 rows
                float c2 = cR[j] * cD + nsR[j] * sD;
                nsR[j] = nsR[j] * cD - cR[j] * sD;
                cR[j] = c2;
            }
            const unsigned short* bt = Bt[cp * 2 + st];
            #pragma unroll
            for (int tn = 0; tn < 4; ++tn) {
                const short8 bf = *(const short8*)&bt[(tn * 16 + l15) * BSTR + hk * 8];
                accC[tn] = __builtin_amdgcn_mfma_f32_16x16x32_bf16(aC, bf, accC[tn], 0, 0, 0);
                accS[tn] = __builtin_amdgcn_mfma_f32_16x16x32_bf16(aS, bf, accS[tn], 0, 0, 0);
            }
        }
    }
#undef STAGE
    // C/D: col=lane&15, row=(lane>>4)*4+reg; pack (Re,Im) -> u32
    unsigned* basew = part_w + (size_t)blockIdx.x * 4096;
    #pragma unroll
    for (int tn = 0; tn < 4; ++tn) {
        #pragma unroll
        for (int r = 0; r < 4; ++r) {
            int k = w * 16 + hk * 4 + r;
            int i = tn * 16 + l15;
            basew[k * 64 + i] = pkbf(accC[tn][r], accS[tn][r]);
        }
    }
}

// ================= K2: reduce packed partials -> uhat (full chip) =================
// 256 blocks x 256 thr; block owns 16 columns j of 4096; 16-way b-interleave.
__global__ __launch_bounds__(256) void fno_red(const unsigned* __restrict__ part_w,
                                               float* __restrict__ uhat) {
    __shared__ float redR[16][17], redI[16][17];
    const int tid = threadIdx.x;
    const int c = tid & 15;
    const int h = tid >> 4;
    const int j0 = blockIdx.x * 16;

    float aR = 0.f, aI = 0.f;
    #pragma unroll 8
    for (int b = h; b < NBF; b += 16) {
        unsigned v = part_w[(size_t)b * 4096 + j0 + c];
        aR += bf2f((unsigned short)(v & 0xffff));
        aI += bf2f((unsigned short)(v >> 16));
    }
    redR[h][c] = aR;
    redI[h][c] = aI;
    __syncthreads();
    if (tid < 32) {
        const int cc = tid & 15;
        float s = 0.f;
        if (tid < 16) {
            #pragma unroll
            for (int hh = 0; hh < 16; ++hh) s += redR[hh][cc];
            uhat[j0 + cc] = s;
        } else {
            #pragma unroll
            for (int hh = 0; hh < 16; ++hh) s += redI[hh][cc];
            uhat[4096 + j0 + cc] = s;
        }
    }
}

// ================= K3: Kc apply (blocks 0..63) + z_local (block 64) =================
__global__ __launch_bounds__(256) void fno_coef(const float* __restrict__ uhat,
                                                const float* __restrict__ Kt,
                                                const float* __restrict__ W,
                                                const float* __restrict__ u,
                                                const float* __restrict__ y,
                                                float* __restrict__ coef) {
    __shared__ float sm[640];
    const int tid = threadIdx.x;
    const int o = tid & 63;
    const int q = tid >> 6;
    if (blockIdx.x == 64) {
        float* zl4 = sm;
        const int idx = (int)(y[0] * (float)LN);
        float zl = 0.f;
        #pragma unroll 4
        for (int ii = q * 16; ii < q * 16 + 16; ++ii)
            zl = fmaf(W[o * 64 + ii], u[(size_t)idx * 64 + ii], zl);
        zl4[q * 64 + o] = zl;
        __syncthreads();
        if (tid < 64)
            coef[8192 + tid] = zl4[tid] + zl4[64 + tid] + zl4[128 + tid] + zl4[192 + tid];
        return;
    }
    const int k = blockIdx.x;
    float* uh = sm;            // [128]
    float* zr4 = sm + 128;     // [4][64] -> reuse as two halves
    float* zi4 = zr4 + 256;
    if (tid < 128) uh[tid] = uhat[(tid >> 6) * 4096 + k * 64 + (tid & 63)];
    __syncthreads();
    float zr = 0.f, zi = 0.f;
    #pragma unroll 4
    for (int ii = q * 16; ii < q * 16 + 16; ++ii) {
        float k0v = Kt[(size_t)(ii * 64 + o) * 64 + k];
        float k1v = Kt[262144 + (size_t)(ii * 64 + o) * 64 + k];
        zr = fmaf(uh[ii], k0v, fmaf(-uh[64 + ii], k1v, zr));
        zi = fmaf(uh[ii], k1v, fmaf(uh[64 + ii], k0v, zi));
    }
    zr4[q * 64 + o] = zr;
    zi4[q * 64 + o] = zi;
    __syncthreads();
    if (tid < 64) {
        float zrs = zr4[tid] + zr4[64 + tid] + zr4[128 + tid] + zr4[192 + tid];
        float zis = zi4[tid] + zi4[64 + tid] + zi4[128 + tid] + zi4[192 + tid];
        if (k == 0) {
            coef[tid] = zrs * INV_L;    // DC: only Re enters irfft
            coef[4096 + tid] = 0.f;
        } else {
            coef[k * 64 + tid] = 2.f * zrs * INV_L;
            coef[4096 + k * 64 + tid] = -2.f * zis * INV_L;
        }
    }
}

// ================= K4: inverse transform =================
// 1024 blocks x 256 thr, launch_bounds(256,3). B-fragments hoisted to regs;
// xpose aliased over Bs (per-wave regions -> NO per-iter barrier).
__global__ __launch_bounds__(256, 3) void fno_inv(const float* __restrict__ coef,
                                                  float* __restrict__ out) {
    __shared__ __align__(16) char ismem[17920];
    unsigned short* Bs = (unsigned short*)ismem;          // 64*ISTR halfs (prologue only)
    float* zloc = (float*)(ismem + 17664);                // 64 f
    const int tid = threadIdx.x;
    const int lane = tid & 63;
    const int w = tid >> 6;
    const int l15 = lane & 15;
    const int hk = lane >> 4;

    for (int e = tid; e < 4096; e += 256) {
        int mm = e >> 6, ch = e & 63;
        Bs[ch * ISTR + mm] = f2bf_t(coef[e]);
        Bs[ch * ISTR + 64 + mm] = f2bf_t(coef[4096 + e]);
    }
    if (tid < 64) zloc[tid] = coef[8192 + tid];
    __syncthreads();

    const int rl = lane >> 4;
    const int cq = lane & 15;
    float4 zv = *(const float4*)&zloc[cq * 4];

    // hoist p-invariant B fragments into registers (once)
    short8 bfr[4][4];
    #pragma unroll
    for (int ks = 0; ks < 4; ++ks)
        #pragma unroll
        for (int tn = 0; tn < 4; ++tn)
            bfr[ks][tn] = *(const short8*)&Bs[(tn * 16 + l15) * ISTR + ks * 32 + hk * 8];
    __syncthreads();   // all waves done reading Bs -> safe to alias xpose over it

    float* xpw = (float*)ismem + w * 16 * XSTR;   // per-wave xpose region

    for (int p = 0; p < 4; ++p) {
        const int nbase = blockIdx.x * 256 + (p * 4 + w) * 16;
        const int row = nbase + l15;
        float cstp = fcos01((float)row * INV_L);
        float sstp = fsin01((float)row * INV_L);

        short8 aF[4];
        #pragma unroll
        for (int h = 0; h < 2; ++h) {
            const int m0 = h * 32 + hk * 8;
            const int ph = (row * m0) & LMASK;
            float c = fcos01((float)ph * INV_L);
            float s = fsin01((float)ph * INV_L);
            float cv[8], sv[8];
            #pragma unroll
            for (int jj = 0; jj < 8; ++jj) {
                cv[jj] = c; sv[jj] = s;
                float c2 = c * cstp - s * sstp;
                s = fmaf(s, cstp, c * sstp);
                c = c2;
            }
            aF[h] = pk8(cv);
            aF[2 + h] = pk8(sv);
        }

        f32x4 acc[4];
        #pragma unroll
        for (int tn = 0; tn < 4; ++tn) acc[tn] = (f32x4){0,0,0,0};
        #pragma unroll
        for (int ks = 0; ks < 4; ++ks)
            #pragma unroll
            for (int tn = 0; tn < 4; ++tn)
                acc[tn] = __builtin_amdgcn_mfma_f32_16x16x32_bf16(aF[ks], bfr[ks][tn], acc[tn], 0, 0, 0);

        #pragma unroll
        for (int tn = 0; tn < 4; ++tn)
            #pragma unroll
            for (int r = 0; r < 4; ++r)
                xpw[(hk * 4 + r) * XSTR + tn * 16 + l15] = acc[tn][r];
        asm volatile("s_waitcnt lgkmcnt(0)" ::: "memory");  // wave-local LDS drain
        #pragma unroll
        for (int rg = 0; rg < 4; ++rg) {
            const int rowl = rg * 4 + rl;
            float4 v = *(const float4*)&xpw[rowl * XSTR + cq * 4];
            v.x += zv.x; v.y += zv.y; v.z += zv.z; v.w += zv.w;
            *(float4*)(out + (size_t)(nbase + rowl) * NCH + cq * 4) = v;
        }
        asm volatile("s_waitcnt lgkmcnt(0)" ::: "memory");  // reads done before next overwrite
    }
}

extern "C" void kernel_launch(void* const* d_in, const int* in_sizes, int n_in,
                              void* d_out, int out_size, void* d_ws, size_t ws_size,
                              hipStream_t stream) {
    const float* u = (const float*)d_in[0];
    const float* y = (const float*)d_in[1];
    const float* K = (const float*)d_in[2];
    const float* W = (const float*)d_in[3];
    float* out = (float*)d_out;

    // ws: part_w u32[512*4096] @0 (8 MiB) | uhat f32 8192 @8 MiB | coef f32 8256
    unsigned* part_w = (unsigned*)d_ws;
    float* uhat = (float*)((char*)d_ws + 8388608);
    float* coef = uhat + 8192;

    fno_fwd<<<NBF, 256, 0, stream>>>(u, part_w);
    fno_red<<<256, 256, 0, stream>>>(part_w, uhat);
    fno_coef<<<65, 256, 0, stream>>>(uhat, K, W, u, y, coef);
    fno_inv<<<1024, 256, 0, stream>>>(coef, out);
}